// Round 12
// baseline (465.553 us; speedup 1.0000x reference)
//
#include <hip/hip_runtime.h>
#include <hip/hip_fp16.h>
#include <cmath>

// ButterflyRotation: 12 layers of stride-2^l Givens rotations on rows of 4096 fp32.
// R8b (compile fix: __builtin_nontemporal_store needs a NATIVE vector type, not
// HIP's float4 class -> use ext_vector_type(4) for the nt store; no other change):
// structural latency attack. R7 post-mortem: compiler sank the pre-barrier
// table loads (VGPR=32 proves it), exposing L2 latency per phase; kernel is
// latency-bound around barrier-separated segments, no pipe >50%.
// New schedule: a wave owns 1024 contiguous elements, so
//   layers 0..3  : intra-thread (stride 1..8)
//   layers 4..9  : intra-wave __shfl_xor, lane mask 1..32 (NO LDS, NO barrier)
//   layers 10..11: after ONE LDS exchange (contiguous b128 both ways,
//                  conflict-free by construction, no padding), in-register.
// 1 barrier total (was 2-3), 1 LDS round-trip (was 2), 0 bank conflicts.
// Table: 96 KiB half2(sin, cos-1), lane-coalesced uint4 rows; shuffle layers
// store one row per thread-PAIR (partner lanes read the same address -> traffic
// merges) with the side sign applied at runtime via one integer xor.

namespace {
constexpr int kDim = 4096;
constexpr int kBatch = 8192;
constexpr int kPairs = kDim / 2;   // 2048
constexpr int kThreads = 256;
// Table geometry in uint4 units (16 B = 4 half2 slots):
//  A: layers 0..3  (in-thread):  idx = l*512 + u*256 + t,        u in [0,2)
//  B: layers 4..9  (shuffle):    idx = 2048 + b*512 + u*128 + row, u in [0,4)
//  C: layers 10..11 (post-exch): idx = 5120 + (l-10)*512 + u*256 + t
constexpr int kTabB = 2048;
constexpr int kTabC = 5120;
constexpr int kTabTotal = 6144;    // uint4s = 96 KiB
}

typedef float float4v __attribute__((ext_vector_type(4)));  // native, nt-store OK

// Precompute: one thread per half2 slot. h = half2 index in [0, kTabTotal*4).
__global__ void bf_precompute(const float* __restrict__ angles,
                              __half2* __restrict__ tab) {
    const int h = blockIdx.x * blockDim.x + threadIdx.x;
    if (h >= kTabTotal * 4) return;
    const int idx = h >> 2;      // uint4 index
    const int pos = h & 3;       // half2 slot within the uint4
    int l, i;                    // layer, LEFT element index of the pair
    if (idx < kTabB) {
        // Segment A: per-pair, elements i = 16t + j, strides 1..8.
        l = idx >> 9;
        const int r = idx & 511;
        const int u = r >> 8, t = r & 255;
        const int q = u * 4 + pos;                       // local pair 0..7
        const int j = ((q >> l) << (l + 1)) | (q & ((1 << l) - 1));
        i = 16 * t + j;
    } else if (idx < kTabC) {
        // Segment B: per-element, UNSIGNED, shared by partner threads t0/t0^m.
        const int e = idx - kTabB;
        const int b = e >> 9;                            // 0..5, stride = 16<<b
        l = 4 + b;
        const int r = e & 511;
        const int u = r >> 7, row = r & 127;
        const int k = u * 4 + pos;                       // element slot 0..15
        const int t0 = ((row >> b) << (b + 1)) | (row & ((1 << b) - 1));
        i = 16 * t0 + k;                                 // left thread's element
    } else {
        // Segment C: per-pair, post-exchange ownership i = 4t + (j&3) + 1024*(j>>2).
        const int e = idx - kTabC;
        l = 10 + (e >> 9);
        const int r = e & 511;
        const int u = r >> 8, t = r & 255;
        const int q = u * 4 + pos;                       // local pair 0..7
        const int j = (l == 10) ? (((q >> 2) << 3) | (q & 3)) : q;
        i = 4 * t + (j & 3) + 1024 * (j >> 2);
    }
    const int s = 1 << l;
    const int p = ((i >> (l + 1)) << l) | (i & (s - 1)); // global pair index
    const float a = angles[l * kPairs + p];
    tab[h] = __floats2half2_rn(sinf(a), cosf(a) - 1.0f);
}

__global__ __launch_bounds__(kThreads, 8)
void bf_butterfly(const float* __restrict__ x,
                  const __half2* __restrict__ tab,
                  float* __restrict__ out) {
    __shared__ float lds[kDim];          // 16 KiB, no padding needed (see below)
    const int t = threadIdx.x;
    const int row = blockIdx.x;
    const uint4* ap = reinterpret_cast<const uint4*>(tab);

    // ---- load: thread t owns contiguous elements [16t, 16t+16) ----
    float v[16];
    {
        const float4* src =
            reinterpret_cast<const float4*>(x + (size_t)row * kDim + 16 * t);
#pragma unroll
        for (int k = 0; k < 4; ++k) {
            const float4 f = src[k];
            v[4 * k + 0] = f.x; v[4 * k + 1] = f.y;
            v[4 * k + 2] = f.z; v[4 * k + 3] = f.w;
        }
    }

    // ---- segment A: layers 0..3, intra-thread pairs (slot xor 1,2,4,8) ----
#pragma unroll
    for (int l = 0; l < 4; ++l) {
        uint4 ta[2];
        ta[0] = ap[l * 512 + t];
        ta[1] = ap[l * 512 + 256 + t];
        const __half2* hh = reinterpret_cast<const __half2*>(ta);
#pragma unroll
        for (int q = 0; q < 8; ++q) {
            const int j  = ((q >> l) << (l + 1)) | (q & ((1 << l) - 1));
            const int jp = j + (1 << l);
            const float2 sc = __half22float2(hh[q]);
            const float s = sc.x, cm1 = sc.y;
            const float xl = v[j], xr = v[jp];
            // new_left = xl + xl*cm1 + xr*s ; new_right = xr + xr*cm1 - xl*s
            v[j]  = fmaf(xl, cm1, fmaf(xr,  s, xl));
            v[jp] = fmaf(xr, cm1, fmaf(-xl, s, xr));
        }
    }

    // ---- segment B: layers 4..9, intra-wave shuffles (lane xor 1..32) ----
#pragma unroll
    for (int b = 0; b < 6; ++b) {
        const int m = 1 << b;                            // lane mask; stride 16<<b
        const int rw = ((t >> (b + 1)) << b) | (t & (m - 1));  // shared row
        uint4 tb[4];
#pragma unroll
        for (int u = 0; u < 4; ++u) tb[u] = ap[kTabB + b * 512 + u * 128 + rw];
        const __half2* hh = reinterpret_cast<const __half2*>(tb);
        const unsigned sgn = (((unsigned)t >> b) & 1u) << 31;  // right side: -s
#pragma unroll
        for (int k = 0; k < 16; ++k) {
            const float2 sc = __half22float2(hh[k]);
            const float se = __uint_as_float(__float_as_uint(sc.x) ^ sgn);
            const float rv = __shfl_xor(v[k], m, 64);
            // new = x + x*cm1 + (+-s)*partner
            v[k] = fmaf(rv, se, fmaf(v[k], sc.y, v[k]));
        }
    }

    // ---- ONE exchange: contiguous write, lane-contiguous read (0 conflicts) ----
#pragma unroll
    for (int k = 0; k < 4; ++k) {
        *reinterpret_cast<float4*>(&lds[16 * t + 4 * k]) =
            make_float4(v[4 * k], v[4 * k + 1], v[4 * k + 2], v[4 * k + 3]);
    }
    __syncthreads();
#pragma unroll
    for (int g = 0; g < 4; ++g) {
        const float4 f = *reinterpret_cast<const float4*>(&lds[4 * t + 1024 * g]);
        v[4 * g + 0] = f.x; v[4 * g + 1] = f.y;
        v[4 * g + 2] = f.z; v[4 * g + 3] = f.w;
    }
    // Now slot k holds element i = 4t + (k&3) + 1024*(k>>2).

    // ---- segment C: layers 10..11, intra-thread (slot xor 4, 8) ----
#pragma unroll
    for (int lc = 0; lc < 2; ++lc) {
        uint4 tc[2];
        tc[0] = ap[kTabC + lc * 512 + t];
        tc[1] = ap[kTabC + lc * 512 + 256 + t];
        const __half2* hh = reinterpret_cast<const __half2*>(tc);
#pragma unroll
        for (int q = 0; q < 8; ++q) {
            const int j  = (lc == 0) ? (((q >> 2) << 3) | (q & 3)) : q;
            const int jp = j + ((lc == 0) ? 4 : 8);
            const float2 sc = __half22float2(hh[q]);
            const float s = sc.x, cm1 = sc.y;
            const float xl = v[j], xr = v[jp];
            v[j]  = fmaf(xl, cm1, fmaf(xr,  s, xl));
            v[jp] = fmaf(xr, cm1, fmaf(-xl, s, xr));
        }
    }

    // ---- store: lane-contiguous float4 at 4t + 1024g, nontemporal ----
    float* dst = out + (size_t)row * kDim + 4 * t;
#pragma unroll
    for (int g = 0; g < 4; ++g) {
        float4v f;
        f.x = v[4 * g]; f.y = v[4 * g + 1]; f.z = v[4 * g + 2]; f.w = v[4 * g + 3];
        __builtin_nontemporal_store(f, reinterpret_cast<float4v*>(dst + 1024 * g));
    }
}

extern "C" void kernel_launch(void* const* d_in, const int* in_sizes, int n_in,
                              void* d_out, int out_size, void* d_ws, size_t ws_size,
                              hipStream_t stream) {
    (void)in_sizes; (void)n_in; (void)out_size; (void)ws_size;
    const float* x = (const float*)d_in[0];
    const float* angles = (const float*)d_in[1];
    // d_in[2]/d_in[3] (left_idx/right_idx) are recomputed analytically.
    __half2* tab = (__half2*)d_ws;   // kTabTotal uint4 = 96 KiB
    float* out = (float*)d_out;

    const int nHalf2 = kTabTotal * 4;
    bf_precompute<<<(nHalf2 + kThreads - 1) / kThreads, kThreads, 0, stream>>>(
        angles, tab);
    bf_butterfly<<<kBatch, kThreads, 0, stream>>>(x, tab, out);
}

// Round 13
// 260.340 us; speedup vs baseline: 1.7883x; 1.7883x over previous
//
#include <hip/hip_runtime.h>
#include <hip/hip_fp16.h>
#include <cmath>

// ButterflyRotation: 12 layers of stride-2^l Givens rotations on rows of 4096 fp32.
// R8c: R8b measured 316us with WRITE_SIZE 737MB / FETCH 443MB / VGPR=32 -> massive
// scratch spill under __launch_bounds__(256,8)'s 64-VGPR cap (segment B needs
// v[16]+tb[16]+temps live through the unrolled shuffle chain). Structure verified
// CORRECT (absmax passed). Single change: (256,8) -> (256,4), cap 128 VGPRs.
// Schedule (unchanged): a wave owns 1024 contiguous elements, so
//   layers 0..3  : intra-thread (stride 1..8)
//   layers 4..9  : intra-wave __shfl_xor, lane mask 1..32 (NO LDS, NO barrier)
//   layers 10..11: after ONE LDS exchange (contiguous b128 both ways,
//                  conflict-free by construction, no padding), in-register.
// 1 barrier total, 1 LDS round-trip. Table: 96 KiB half2(sin, cos-1),
// lane-coalesced uint4 rows; shuffle layers share one row per thread-pair with
// the side sign applied via one integer xor.

namespace {
constexpr int kDim = 4096;
constexpr int kBatch = 8192;
constexpr int kPairs = kDim / 2;   // 2048
constexpr int kThreads = 256;
// Table geometry in uint4 units (16 B = 4 half2 slots):
//  A: layers 0..3  (in-thread):  idx = l*512 + u*256 + t,        u in [0,2)
//  B: layers 4..9  (shuffle):    idx = 2048 + b*512 + u*128 + row, u in [0,4)
//  C: layers 10..11 (post-exch): idx = 5120 + (l-10)*512 + u*256 + t
constexpr int kTabB = 2048;
constexpr int kTabC = 5120;
constexpr int kTabTotal = 6144;    // uint4s = 96 KiB
}

typedef float float4v __attribute__((ext_vector_type(4)));  // native, nt-store OK

// Precompute: one thread per half2 slot. h = half2 index in [0, kTabTotal*4).
__global__ void bf_precompute(const float* __restrict__ angles,
                              __half2* __restrict__ tab) {
    const int h = blockIdx.x * blockDim.x + threadIdx.x;
    if (h >= kTabTotal * 4) return;
    const int idx = h >> 2;      // uint4 index
    const int pos = h & 3;       // half2 slot within the uint4
    int l, i;                    // layer, LEFT element index of the pair
    if (idx < kTabB) {
        // Segment A: per-pair, elements i = 16t + j, strides 1..8.
        l = idx >> 9;
        const int r = idx & 511;
        const int u = r >> 8, t = r & 255;
        const int q = u * 4 + pos;                       // local pair 0..7
        const int j = ((q >> l) << (l + 1)) | (q & ((1 << l) - 1));
        i = 16 * t + j;
    } else if (idx < kTabC) {
        // Segment B: per-element, UNSIGNED, shared by partner threads t0/t0^m.
        const int e = idx - kTabB;
        const int b = e >> 9;                            // 0..5, stride = 16<<b
        l = 4 + b;
        const int r = e & 511;
        const int u = r >> 7, row = r & 127;
        const int k = u * 4 + pos;                       // element slot 0..15
        const int t0 = ((row >> b) << (b + 1)) | (row & ((1 << b) - 1));
        i = 16 * t0 + k;                                 // left thread's element
    } else {
        // Segment C: per-pair, post-exchange ownership i = 4t + (j&3) + 1024*(j>>2).
        const int e = idx - kTabC;
        l = 10 + (e >> 9);
        const int r = e & 511;
        const int u = r >> 8, t = r & 255;
        const int q = u * 4 + pos;                       // local pair 0..7
        const int j = (l == 10) ? (((q >> 2) << 3) | (q & 3)) : q;
        i = 4 * t + (j & 3) + 1024 * (j >> 2);
    }
    const int s = 1 << l;
    const int p = ((i >> (l + 1)) << l) | (i & (s - 1)); // global pair index
    const float a = angles[l * kPairs + p];
    tab[h] = __floats2half2_rn(sinf(a), cosf(a) - 1.0f);
}

__global__ __launch_bounds__(kThreads, 4)
void bf_butterfly(const float* __restrict__ x,
                  const __half2* __restrict__ tab,
                  float* __restrict__ out) {
    __shared__ float lds[kDim];          // 16 KiB, no padding needed (see below)
    const int t = threadIdx.x;
    const int row = blockIdx.x;
    const uint4* ap = reinterpret_cast<const uint4*>(tab);

    // ---- load: thread t owns contiguous elements [16t, 16t+16) ----
    float v[16];
    {
        const float4* src =
            reinterpret_cast<const float4*>(x + (size_t)row * kDim + 16 * t);
#pragma unroll
        for (int k = 0; k < 4; ++k) {
            const float4 f = src[k];
            v[4 * k + 0] = f.x; v[4 * k + 1] = f.y;
            v[4 * k + 2] = f.z; v[4 * k + 3] = f.w;
        }
    }

    // ---- segment A: layers 0..3, intra-thread pairs (slot xor 1,2,4,8) ----
#pragma unroll
    for (int l = 0; l < 4; ++l) {
        uint4 ta[2];
        ta[0] = ap[l * 512 + t];
        ta[1] = ap[l * 512 + 256 + t];
        const __half2* hh = reinterpret_cast<const __half2*>(ta);
#pragma unroll
        for (int q = 0; q < 8; ++q) {
            const int j  = ((q >> l) << (l + 1)) | (q & ((1 << l) - 1));
            const int jp = j + (1 << l);
            const float2 sc = __half22float2(hh[q]);
            const float s = sc.x, cm1 = sc.y;
            const float xl = v[j], xr = v[jp];
            // new_left = xl + xl*cm1 + xr*s ; new_right = xr + xr*cm1 - xl*s
            v[j]  = fmaf(xl, cm1, fmaf(xr,  s, xl));
            v[jp] = fmaf(xr, cm1, fmaf(-xl, s, xr));
        }
    }

    // ---- segment B: layers 4..9, intra-wave shuffles (lane xor 1..32) ----
#pragma unroll
    for (int b = 0; b < 6; ++b) {
        const int m = 1 << b;                            // lane mask; stride 16<<b
        const int rw = ((t >> (b + 1)) << b) | (t & (m - 1));  // shared row
        uint4 tb[4];
#pragma unroll
        for (int u = 0; u < 4; ++u) tb[u] = ap[kTabB + b * 512 + u * 128 + rw];
        const __half2* hh = reinterpret_cast<const __half2*>(tb);
        const unsigned sgn = (((unsigned)t >> b) & 1u) << 31;  // right side: -s
#pragma unroll
        for (int k = 0; k < 16; ++k) {
            const float2 sc = __half22float2(hh[k]);
            const float se = __uint_as_float(__float_as_uint(sc.x) ^ sgn);
            const float rv = __shfl_xor(v[k], m, 64);
            // new = x + x*cm1 + (+-s)*partner
            v[k] = fmaf(rv, se, fmaf(v[k], sc.y, v[k]));
        }
    }

    // ---- ONE exchange: contiguous write, lane-contiguous read (0 conflicts) ----
#pragma unroll
    for (int k = 0; k < 4; ++k) {
        *reinterpret_cast<float4*>(&lds[16 * t + 4 * k]) =
            make_float4(v[4 * k], v[4 * k + 1], v[4 * k + 2], v[4 * k + 3]);
    }
    __syncthreads();
#pragma unroll
    for (int g = 0; g < 4; ++g) {
        const float4 f = *reinterpret_cast<const float4*>(&lds[4 * t + 1024 * g]);
        v[4 * g + 0] = f.x; v[4 * g + 1] = f.y;
        v[4 * g + 2] = f.z; v[4 * g + 3] = f.w;
    }
    // Now slot k holds element i = 4t + (k&3) + 1024*(k>>2).

    // ---- segment C: layers 10..11, intra-thread (slot xor 4, 8) ----
#pragma unroll
    for (int lc = 0; lc < 2; ++lc) {
        uint4 tc[2];
        tc[0] = ap[kTabC + lc * 512 + t];
        tc[1] = ap[kTabC + lc * 512 + 256 + t];
        const __half2* hh = reinterpret_cast<const __half2*>(tc);
#pragma unroll
        for (int q = 0; q < 8; ++q) {
            const int j  = (lc == 0) ? (((q >> 2) << 3) | (q & 3)) : q;
            const int jp = j + ((lc == 0) ? 4 : 8);
            const float2 sc = __half22float2(hh[q]);
            const float s = sc.x, cm1 = sc.y;
            const float xl = v[j], xr = v[jp];
            v[j]  = fmaf(xl, cm1, fmaf(xr,  s, xl));
            v[jp] = fmaf(xr, cm1, fmaf(-xl, s, xr));
        }
    }

    // ---- store: lane-contiguous float4 at 4t + 1024g, nontemporal ----
    float* dst = out + (size_t)row * kDim + 4 * t;
#pragma unroll
    for (int g = 0; g < 4; ++g) {
        float4v f;
        f.x = v[4 * g]; f.y = v[4 * g + 1]; f.z = v[4 * g + 2]; f.w = v[4 * g + 3];
        __builtin_nontemporal_store(f, reinterpret_cast<float4v*>(dst + 1024 * g));
    }
}

extern "C" void kernel_launch(void* const* d_in, const int* in_sizes, int n_in,
                              void* d_out, int out_size, void* d_ws, size_t ws_size,
                              hipStream_t stream) {
    (void)in_sizes; (void)n_in; (void)out_size; (void)ws_size;
    const float* x = (const float*)d_in[0];
    const float* angles = (const float*)d_in[1];
    // d_in[2]/d_in[3] (left_idx/right_idx) are recomputed analytically.
    __half2* tab = (__half2*)d_ws;   // kTabTotal uint4 = 96 KiB
    float* out = (float*)d_out;

    const int nHalf2 = kTabTotal * 4;
    bf_precompute<<<(nHalf2 + kThreads - 1) / kThreads, kThreads, 0, stream>>>(
        angles, tab);
    bf_butterfly<<<kBatch, kThreads, 0, stream>>>(x, tab, out);
}